// Round 7
// baseline (588.150 us; speedup 1.0000x reference)
//
#include <hip/hip_runtime.h>
#include <cstdint>
#include <cstddef>

#define NV 50000
#define ED 128
#define SS 50
#define NB 128
#define NM 200
#define BMD (NB*NM*ED)   // 3,276,800 floats per table
#define NCH 32
#define CHD 1563         // ceil(50000/32)

typedef _Float16 f16x8 __attribute__((ext_vector_type(8)));
typedef _Float16 f16x4 __attribute__((ext_vector_type(4)));
typedef _Float16 f16x2 __attribute__((ext_vector_type(2)));
typedef float    f32x4 __attribute__((ext_vector_type(4)));

// ---------------------------------------------------------------------------
// Kernel P: C3 fp32 -> f16. Tables 0-2 must stay fp32 (fp16 score path fails:
// r1 0.195 / r3 0.316 vs thr 0.056). LLC warm refuted (r4). 2-wide unroll
// refuted (r5). 8bm/block refuted (r6: FETCH 566->743MB — dedup needs big
// blocks). Duration tracks FETCH linearly in every probe => fetch-bound.
// ---------------------------------------------------------------------------
__global__ __launch_bounds__(256) void cvt_c3_k(
    const float* __restrict__ src, _Float16* __restrict__ dst) {
  const int i = blockIdx.x * 256 + threadIdx.x;   // f16x8 group, < 800000
  const float4* s4 = (const float4*)src;
  float4 f0 = s4[2 * (size_t)i];
  float4 f1 = s4[2 * (size_t)i + 1];
  f16x8 h;
  h[0] = (_Float16)f0.x; h[1] = (_Float16)f0.y;
  h[2] = (_Float16)f0.z; h[3] = (_Float16)f0.w;
  h[4] = (_Float16)f1.x; h[5] = (_Float16)f1.y;
  h[6] = (_Float16)f1.z; h[7] = (_Float16)f1.w;
  *(f16x8*)(dst + (size_t)8 * i) = h;
}

// ---------------------------------------------------------------------------
// Kernel A: vocab-chunked gather-reduce, TABLE-SPLIT + XCD AFFINITY.
// blockIdx = j*8 + s; s in [0,8): table = s>>1. With round-robin workgroup->
// XCD dispatch (the mapping XCD-swizzle relies on), table k's blocks land on
// XCDs {2k,2k+1} only, so each XCD's L2 touches ONE table: compulsory fetch
// drops from ~8x89.6MB-coverage (566MB) to ~2x per table (~180MB).
// r2's 16bm/block geometry kept (proven best L2 dedup). Bit-identical Mt.
// ---------------------------------------------------------------------------
__global__ __launch_bounds__(256) void story_embed_k(
    const int* __restrict__ story, const float* __restrict__ C,
    const _Float16* __restrict__ C3h, float* __restrict__ Mt) {
  const int s8    = blockIdx.x & 7;
  const int table = s8 >> 1;                       // 0..3
  const int bmset = (blockIdx.x >> 3) * 2 + (s8 & 1);  // 0..1599
  const int wave = threadIdx.x >> 6;
  const int lane = threadIdx.x & 63;
  const int bm0 = bmset * 16;
  const int sl = (lane < SS) ? lane : (SS - 1);

  int idxg[4], cidg[4];
#pragma unroll
  for (int gg = 0; gg < 4; ++gg) {
    const int bm = bm0 + wave + 4 * gg;
    idxg[gg] = story[(size_t)bm * SS + sl];
    cidg[gg] = (lane < SS) ? (idxg[gg] / CHD) : -1;
  }
  const float a0 = ((float)(2*lane + 1) - 64.5f) * 6.25e-4f;
  const float a1 = ((float)(2*lane + 2) - 64.5f) * 6.25e-4f;
  float2 acc[4];
#pragma unroll
  for (int gg = 0; gg < 4; ++gg) acc[gg] = make_float2(0.f, 0.f);

  const float* Ct = C + (size_t)table * NV * ED + 2 * lane;   // tables 0-2
  const _Float16* C3t = C3h + 2 * lane;                       // table 3
  const bool t3 = (table == 3);

  for (int c = 0; c < NCH; ++c) {
#pragma unroll
    for (int gg = 0; gg < 4; ++gg) {
      unsigned long long mask = __ballot(cidg[gg] == c);
      while (mask) {
        const int s = __builtin_ctzll(mask);
        mask &= mask - 1;
        const int row = __shfl(idxg[gg], s);
        float e0, e1;
        if (s == SS - 1) { e0 = 1.0f; e1 = 1.0f; }
        else {
          float js = (float)(s + 1) - 25.5f;
          e0 = fmaf(a0, js, 1.0f);
          e1 = fmaf(a1, js, 1.0f);
        }
        float cx, cy;
        if (t3) {                       // block-uniform branch (no divergence)
          f16x2 cv = *(const f16x2*)(C3t + (size_t)row * ED);
          cx = (float)cv[0]; cy = (float)cv[1];
        } else {
          float2 cv = *(const float2*)(Ct + (size_t)row * ED);
          cx = cv.x; cy = cv.y;
        }
        acc[gg].x = fmaf(e0, cx, acc[gg].x);
        acc[gg].y = fmaf(e1, cy, acc[gg].y);
      }
    }
    __syncthreads();
  }

#pragma unroll
  for (int gg = 0; gg < 4; ++gg) {
    const int bm = bm0 + wave + 4 * gg;
    *(float2*)(Mt + (size_t)table * BMD + (size_t)bm * ED + 2 * lane) = acc[gg];
  }
}

// ---------------------------------------------------------------------------
// Kernel B: per-batch hop loop. NEW: all three hops' pf tiles (Mt tables
// 1-3, 150 floats/thread) are loaded in the PROLOGUE — the hop loop's
// critical path has no global loads left. Arithmetic identical to r2 (loads
// only reordered). Macro (not runtime-indexed arrays) keeps regs static.
// ---------------------------------------------------------------------------
__global__ __launch_bounds__(512, 2) void hops_k(
    const int* __restrict__ query, const float* __restrict__ C,
    const float* __restrict__ Tw, const float* __restrict__ Tb,
    const float* __restrict__ Mt, float* __restrict__ U) {
  const int b = blockIdx.x;
  const int tid = threadIdx.x;                   // 0..511
  const int d = tid & 127;
  const int p = tid >> 7;                        // 0..3
  const int wave = tid >> 6, lane = tid & 63;
  __shared__ float tile[NM * ED];                // 102,400 B
  __shared__ float u[ED];
  __shared__ float part[512];
  __shared__ float sc[NM];
  __shared__ float o[ED];

  // ---- stage T0 -> LDS (6400 float4; 13 reg-buffered per thread)
  {
    const float4* s4 = (const float4*)(Mt + (size_t)b * NM * ED);
    float4* t4 = (float4*)tile;
    float4 st[13];
#pragma unroll
    for (int j = 0; j < 13; ++j) {
      int i = tid + 512 * j;
      st[j] = (i < NM * ED / 4) ? s4[i] : make_float4(0.f, 0.f, 0.f, 0.f);
    }
#pragma unroll
    for (int j = 0; j < 13; ++j) {
      int i = tid + 512 * j;
      if (i < NM * ED / 4) t4[i] = st[j];
    }
  }

  // ---- prologue pf prefetch: all 3 hops' o-tiles into registers
  float pf0[50], pf1[50], pf2[50];
  {
    const float* T1 = Mt + (size_t)1 * BMD + (size_t)b * NM * ED;
    const float* T2 = Mt + (size_t)2 * BMD + (size_t)b * NM * ED;
    const float* T3 = Mt + (size_t)3 * BMD + (size_t)b * NM * ED;
#pragma unroll
    for (int j = 0; j < 50; ++j) pf0[j] = T1[(size_t)(p + 4 * j) * ED + d];
#pragma unroll
    for (int j = 0; j < 50; ++j) pf1[j] = T2[(size_t)(p + 4 * j) * ED + d];
#pragma unroll
    for (int j = 0; j < 50; ++j) pf2[j] = T3[(size_t)(p + 4 * j) * ED + d];
  }

  // ---- u0 = sum_s enc[s][d] * C0[query[b][s]][d]
  {
    const float ad = ((float)(d + 1) - 64.5f) * 6.25e-4f;
    int rows[13];
#pragma unroll
    for (int j = 0; j < 13; ++j) {
      int s = p + 4 * j;
      rows[j] = query[b * SS + (s < SS ? s : 0)];
    }
    float cv[13];
#pragma unroll
    for (int j = 0; j < 13; ++j)
      cv[j] = C[(size_t)rows[j] * ED + d];
    float accv = 0.f;
#pragma unroll
    for (int j = 0; j < 13; ++j) {
      int s = p + 4 * j;
      float e;
      if (s >= SS) e = 0.f;
      else if (s == SS - 1) e = 1.0f;
      else e = fmaf(ad, (float)(s + 1) - 25.5f, 1.0f);
      accv = fmaf(e, cv[j], accv);
    }
    part[tid] = accv;
  }
  __syncthreads();
  if (tid < ED)
    u[tid] = part[tid] + part[tid + 128] + part[tid + 256] + part[tid + 384];
  __syncthreads();

#define HOP_BODY(PF, UPDATE_TILE)                                             \
  {                                                                           \
    {                                                                         \
      float u0v = u[2 * lane], u1v = u[2 * lane + 1];                         \
      for (int m = wave; m < NM; m += 16) {                                   \
        const int m2 = m + 8;                                                 \
        const bool has2 = (m2 < NM);                                          \
        float2 r0 = *(const float2*)&tile[m * ED + 2 * lane];                 \
        float pa = r0.x * u0v + r0.y * u1v;                                   \
        float pb = 0.f;                                                       \
        if (has2) {                                                           \
          float2 r1 = *(const float2*)&tile[m2 * ED + 2 * lane];              \
          pb = r1.x * u0v + r1.y * u1v;                                       \
        }                                                                     \
        _Pragma("unroll")                                                     \
        for (int off = 32; off; off >>= 1) {                                  \
          pa += __shfl_xor(pa, off);                                          \
          pb += __shfl_xor(pb, off);                                          \
        }                                                                     \
        if (lane == 0) {                                                      \
          sc[m] = pa;                                                         \
          if (has2) sc[m2] = pb;                                              \
        }                                                                     \
      }                                                                       \
    }                                                                         \
    __syncthreads();                                                          \
    float v = (tid < NM) ? sc[tid] : -1e30f;                                  \
    {                                                                         \
      float t = v;                                                            \
      _Pragma("unroll")                                                       \
      for (int off = 32; off; off >>= 1) t = fmaxf(t, __shfl_xor(t, off));    \
      if (lane == 0) part[wave] = t;                                          \
    }                                                                         \
    __syncthreads();                                                          \
    float mx = part[0];                                                       \
    _Pragma("unroll")                                                         \
    for (int w = 1; w < 8; ++w) mx = fmaxf(mx, part[w]);                      \
    float ev = 0.f;                                                           \
    if (tid < NM) { ev = __expf(v - mx); sc[tid] = ev; }                      \
    {                                                                         \
      float t = ev;                                                           \
      _Pragma("unroll")                                                       \
      for (int off = 32; off; off >>= 1) t += __shfl_xor(t, off);             \
      if (lane == 0) part[8 + wave] = t;                                      \
    }                                                                         \
    __syncthreads();                                                          \
    float tot = part[8];                                                      \
    _Pragma("unroll")                                                         \
    for (int w = 9; w < 16; ++w) tot += part[w];                              \
    const float inv = 1.0f / tot;                                             \
    __syncthreads();                                                          \
    {                                                                         \
      float oacc = 0.f;                                                       \
      _Pragma("unroll")                                                       \
      for (int j = 0; j < 50; ++j)                                            \
        oacc = fmaf(sc[p + 4 * j], PF[j], oacc);                              \
      part[tid] = oacc;                                                       \
    }                                                                         \
    if (UPDATE_TILE) {                                                        \
      _Pragma("unroll")                                                       \
      for (int j = 0; j < 50; ++j)                                            \
        tile[(p + 4 * j) * ED + d] = PF[j];                                   \
    }                                                                         \
    __syncthreads();                                                          \
    if (tid < ED)                                                             \
      o[tid] = (part[tid] + part[tid + 128] + part[tid + 256]                 \
                + part[tid + 384]) * inv;                                     \
    __syncthreads();                                                          \
    {                                                                         \
      const float4* twr = (const float4*)(Tw + (size_t)d * ED + p * 32);      \
      float4 tw4[8];                                                          \
      _Pragma("unroll")                                                       \
      for (int j = 0; j < 8; ++j) tw4[j] = twr[j];                            \
      float tacc = 0.f;                                                       \
      _Pragma("unroll")                                                       \
      for (int j = 0; j < 8; ++j) {                                           \
        tacc = fmaf(u[p * 32 + 4 * j + 0], tw4[j].x, tacc);                   \
        tacc = fmaf(u[p * 32 + 4 * j + 1], tw4[j].y, tacc);                   \
        tacc = fmaf(u[p * 32 + 4 * j + 2], tw4[j].z, tacc);                   \
        tacc = fmaf(u[p * 32 + 4 * j + 3], tw4[j].w, tacc);                   \
      }                                                                       \
      part[tid] = tacc;                                                       \
    }                                                                         \
    __syncthreads();                                                          \
    if (tid < ED) {                                                           \
      float dot = part[tid] + part[tid + 128] + part[tid + 256]               \
                  + part[tid + 384] + Tb[tid];                                \
      float tk = 1.0f / (1.0f + __expf(-dot));                                \
      u[tid] = (1.0f - tk) * u[tid] + o[tid] * tk;                            \
    }                                                                         \
    __syncthreads();                                                          \
  }

  HOP_BODY(pf0, true)
  HOP_BODY(pf1, true)
  HOP_BODY(pf2, false)
#undef HOP_BODY

  if (tid < ED) U[(size_t)b * ED + tid] = u[tid];
}

// ---------------------------------------------------------------------------
// Kernel C: a_hat = U @ C3^T via f16 MFMA (r6 version: 512 thr, 128 v/block).
// ---------------------------------------------------------------------------
__global__ __launch_bounds__(512) void out_mm_mfma_k(
    const float* __restrict__ U, const _Float16* __restrict__ C3h,
    float* __restrict__ out) {
  __shared__ _Float16 Ub[ED * 136];   // 34,816 B
  const int tid = threadIdx.x;

  {
    const float4* u4 = (const float4*)U;
#pragma unroll
    for (int j = 0; j < 8; ++j) {
      int i = tid + 512 * j;          // float4 index
      float4 f = u4[i];
      int row = i >> 5;
      int col = (i & 31) * 4;
      f16x4 h;
      h[0] = (_Float16)f.x; h[1] = (_Float16)f.y;
      h[2] = (_Float16)f.z; h[3] = (_Float16)f.w;
      *(f16x4*)&Ub[row * 136 + col] = h;
    }
  }
  __syncthreads();

  const int wave = tid >> 6, lane = tid & 63;
  const int n = lane & 15, q = lane >> 4;
  const int v = blockIdx.x * 128 + wave * 16 + n;
  const bool vok = (v < NV);

  f32x4 acc[8];
#pragma unroll
  for (int mt = 0; mt < 8; ++mt) acc[mt] = (f32x4){0.f, 0.f, 0.f, 0.f};

#pragma unroll
  for (int kt = 0; kt < 4; ++kt) {
    f16x8 bfrag = {};
    if (vok) bfrag = *(const f16x8*)(C3h + (size_t)v * ED + kt * 32 + q * 8);
#pragma unroll
    for (int mt = 0; mt < 8; ++mt) {
      f16x8 afrag = *(const f16x8*)&Ub[(mt * 16 + n) * 136 + kt * 32 + q * 8];
      acc[mt] = __builtin_amdgcn_mfma_f32_16x16x32_f16(afrag, bfrag, acc[mt],
                                                       0, 0, 0);
    }
  }

  if (vok) {
#pragma unroll
    for (int mt = 0; mt < 8; ++mt)
#pragma unroll
      for (int i = 0; i < 4; ++i)
        out[(size_t)(mt * 16 + q * 4 + i) * NV + v] = acc[mt][i];
  }
}

// ---------------------------------------------------------------------------
extern "C" void kernel_launch(void* const* d_in, const int* in_sizes, int n_in,
                              void* d_out, int out_size, void* d_ws, size_t ws_size,
                              hipStream_t stream) {
  const int*   story = (const int*)d_in[0];   // [128,200,50]
  const int*   query = (const int*)d_in[1];   // [128,50]
  const float* C     = (const float*)d_in[2]; // [4,50000,128]
  const float* Tw    = (const float*)d_in[3]; // [128,128]
  const float* Tb    = (const float*)d_in[4]; // [128]
  float* out = (float*)d_out;                 // [128,50000]

  float* wsf = (float*)d_ws;
  float*     Mt  = wsf;                                   // 4*BMD floats
  float*     U   = wsf + (size_t)4 * BMD;                 // 16384 floats
  _Float16*  C3h = (_Float16*)(wsf + (size_t)4 * BMD + NB * ED);

  hipLaunchKernelGGL(cvt_c3_k, dim3(NV * ED / 8 / 256), dim3(256), 0, stream,
                     C + (size_t)3 * NV * ED, C3h);
  // 4 tables x 1600 bm-sets; blockIdx%8 encodes (table,sub) for XCD affinity
  hipLaunchKernelGGL(story_embed_k, dim3(4 * NB * NM / 16), dim3(256), 0,
                     stream, story, C, C3h, Mt);
  hipLaunchKernelGGL(hops_k, dim3(NB), dim3(512), 0, stream,
                     query, C, Tw, Tb, Mt, U);
  hipLaunchKernelGGL(out_mm_mfma_k, dim3((NV + 127) / 128), dim3(512), 0, stream,
                     U, C3h, out);
}

// Round 9
// 357.942 us; speedup vs baseline: 1.6431x; 1.6431x over previous
//
#include <hip/hip_runtime.h>
#include <cstdint>
#include <cstddef>

#define NV 50000
#define ED 128
#define SS 50
#define NB 128
#define NM 200
#define BMD (NB*NM*ED)   // 3,276,800 floats per table
#define NCH 32
#define CHD 1563         // ceil(50000/32)

typedef _Float16 f16x8 __attribute__((ext_vector_type(8)));
typedef _Float16 f16x4 __attribute__((ext_vector_type(4)));
typedef _Float16 f16x2 __attribute__((ext_vector_type(2)));
typedef float    f32x4 __attribute__((ext_vector_type(4)));

// ---------------------------------------------------------------------------
// LEDGER: fp16 score-path REFUTED (r1/r3). LLC warm REFUTED (r4). 2-wide
// unroll REFUTED (r5: FETCH +52%). 8bm/block REFUTED (r6: FETCH +31%).
// Table-split XCD affinity: fetch 377MB CONFIRMED but 1-load/iter kills MLP
// (r7: 424us @ 1TB/s) — r2's 4-table loop = 4-deep MLP is the local optimum.
// r8 was an infra failure; this is the r7 proposal resubmitted unchanged.
// ---------------------------------------------------------------------------
__global__ __launch_bounds__(256) void cvt_c3_k(
    const float* __restrict__ src, _Float16* __restrict__ dst) {
  const int i = blockIdx.x * 256 + threadIdx.x;   // f16x8 group, < 800000
  const float4* s4 = (const float4*)src;
  float4 f0 = s4[2 * (size_t)i];
  float4 f1 = s4[2 * (size_t)i + 1];
  f16x8 h;
  h[0] = (_Float16)f0.x; h[1] = (_Float16)f0.y;
  h[2] = (_Float16)f0.z; h[3] = (_Float16)f0.w;
  h[4] = (_Float16)f1.x; h[5] = (_Float16)f1.y;
  h[6] = (_Float16)f1.z; h[7] = (_Float16)f1.w;
  *(f16x8*)(dst + (size_t)8 * i) = h;
}

// ---------------------------------------------------------------------------
// Kernel A: vocab-chunked gather-reduce — r2-EXACT (measured 193us, 566MB).
// ---------------------------------------------------------------------------
__global__ __launch_bounds__(256) void story_embed_k(
    const int* __restrict__ story, const float* __restrict__ C,
    const _Float16* __restrict__ C3h, float* __restrict__ Mt) {
  const int wave = threadIdx.x >> 6;
  const int lane = threadIdx.x & 63;
  const int bm0 = blockIdx.x * 16;
  const int sl = (lane < SS) ? lane : (SS - 1);

  int idxg[4], cidg[4];
#pragma unroll
  for (int gg = 0; gg < 4; ++gg) {
    const int bm = bm0 + wave + 4 * gg;
    idxg[gg] = story[(size_t)bm * SS + sl];
    cidg[gg] = (lane < SS) ? (idxg[gg] / CHD) : -1;
  }
  const float a0 = ((float)(2*lane + 1) - 64.5f) * 6.25e-4f;
  const float a1 = ((float)(2*lane + 2) - 64.5f) * 6.25e-4f;
  float2 acc[4][4];
#pragma unroll
  for (int gg = 0; gg < 4; ++gg)
#pragma unroll
    for (int k = 0; k < 4; ++k) acc[gg][k] = make_float2(0.f, 0.f);

  for (int c = 0; c < NCH; ++c) {
#pragma unroll
    for (int gg = 0; gg < 4; ++gg) {
      unsigned long long mask = __ballot(cidg[gg] == c);
      while (mask) {
        const int s = __builtin_ctzll(mask);
        mask &= mask - 1;
        const int row = __shfl(idxg[gg], s);
        float e0, e1;
        if (s == SS - 1) { e0 = 1.0f; e1 = 1.0f; }
        else {
          float js = (float)(s + 1) - 25.5f;
          e0 = fmaf(a0, js, 1.0f);
          e1 = fmaf(a1, js, 1.0f);
        }
        const float* base = C + (size_t)row * ED + 2 * lane;
#pragma unroll
        for (int k = 0; k < 3; ++k) {
          float2 cv = *(const float2*)(base + (size_t)k * NV * ED);
          acc[gg][k].x = fmaf(e0, cv.x, acc[gg][k].x);
          acc[gg][k].y = fmaf(e1, cv.y, acc[gg][k].y);
        }
        f16x2 cv3 = *(const f16x2*)(C3h + (size_t)row * ED + 2 * lane);
        acc[gg][3].x = fmaf(e0, (float)cv3[0], acc[gg][3].x);
        acc[gg][3].y = fmaf(e1, (float)cv3[1], acc[gg][3].y);
      }
    }
    __syncthreads();
  }

#pragma unroll
  for (int gg = 0; gg < 4; ++gg) {
    const int bm = bm0 + wave + 4 * gg;
#pragma unroll
    for (int k = 0; k < 4; ++k)
      *(float2*)(Mt + (size_t)k * BMD + (size_t)bm * ED + 2 * lane) = acc[gg][k];
  }
}

// ---------------------------------------------------------------------------
// Kernel B: per-batch hop loop — BARRIER-COMPRESSED: 4 barriers/hop (was 8).
// Softmax is computed redundantly per-wave (max+sum over 200 in-register via
// shfl — removes 4 cross-wave reduce phases); o-partial and Tw-partial fused
// into one dual-reduction phase; o and gate computed in-register by tid<128.
// Only summation ORDER changes vs r2 (fp32 drift ~1e-7, headroom 0.040).
// ---------------------------------------------------------------------------
__global__ __launch_bounds__(512, 2) void hops_k(
    const int* __restrict__ query, const float* __restrict__ C,
    const float* __restrict__ Tw, const float* __restrict__ Tb,
    const float* __restrict__ Mt, float* __restrict__ U) {
  const int b = blockIdx.x;
  const int tid = threadIdx.x;                   // 0..511
  const int d = tid & 127;
  const int p = tid >> 7;                        // 0..3
  const int wave = tid >> 6, lane = tid & 63;
  __shared__ float tile[NM * ED];                // 102,400 B
  __shared__ float u[ED];
  __shared__ float part[512];
  __shared__ float part2[512];
  __shared__ float sc[NM];
  __shared__ float sc2[NM];

  // ---- stage T0 -> LDS (6400 float4; 13 reg-buffered per thread)
  {
    const float4* s4 = (const float4*)(Mt + (size_t)b * NM * ED);
    float4* t4 = (float4*)tile;
    float4 st[13];
#pragma unroll
    for (int j = 0; j < 13; ++j) {
      int i = tid + 512 * j;
      st[j] = (i < NM * ED / 4) ? s4[i] : make_float4(0.f, 0.f, 0.f, 0.f);
    }
#pragma unroll
    for (int j = 0; j < 13; ++j) {
      int i = tid + 512 * j;
      if (i < NM * ED / 4) t4[i] = st[j];
    }
  }

  // ---- u0 = sum_s enc[s][d] * C0[query[b][s]][d]
  {
    const float ad = ((float)(d + 1) - 64.5f) * 6.25e-4f;
    int rows[13];
#pragma unroll
    for (int j = 0; j < 13; ++j) {
      int s = p + 4 * j;
      rows[j] = query[b * SS + (s < SS ? s : 0)];
    }
    float cv[13];
#pragma unroll
    for (int j = 0; j < 13; ++j)
      cv[j] = C[(size_t)rows[j] * ED + d];
    float accv = 0.f;
#pragma unroll
    for (int j = 0; j < 13; ++j) {
      int s = p + 4 * j;
      float e;
      if (s >= SS) e = 0.f;
      else if (s == SS - 1) e = 1.0f;
      else e = fmaf(ad, (float)(s + 1) - 25.5f, 1.0f);
      accv = fmaf(e, cv[j], accv);
    }
    part[tid] = accv;
  }
  __syncthreads();
  if (tid < ED)
    u[tid] = part[tid] + part[tid + 128] + part[tid + 256] + part[tid + 384];
  __syncthreads();

  for (int hop = 0; hop < 3; ++hop) {
    const float* Tn = Mt + (size_t)(hop + 1) * BMD + (size_t)b * NM * ED;
    float pf[50];
#pragma unroll
    for (int j = 0; j < 50; ++j)
      pf[j] = Tn[(size_t)(p + 4 * j) * ED + d];

    // ---- scores -> sc[]
    {
      float u0v = u[2 * lane], u1v = u[2 * lane + 1];
      for (int m = wave; m < NM; m += 16) {
        const int m2 = m + 8;
        const bool has2 = (m2 < NM);
        float2 r0 = *(const float2*)&tile[m * ED + 2 * lane];
        float pa = r0.x * u0v + r0.y * u1v;
        float pb = 0.f;
        if (has2) {
          float2 r1 = *(const float2*)&tile[m2 * ED + 2 * lane];
          pb = r1.x * u0v + r1.y * u1v;
        }
#pragma unroll
        for (int off = 32; off; off >>= 1) {
          pa += __shfl_xor(pa, off);
          pb += __shfl_xor(pb, off);
        }
        if (lane == 0) {
          sc[m] = pa;
          if (has2) sc[m2] = pb;
        }
      }
    }
    __syncthreads();                               // B1: raw scores ready

    // ---- per-wave redundant softmax (no cross-wave phases)
    const bool has3 = (lane + 192 < NM);           // lane < 8
    float v0 = sc[lane];
    float v1 = sc[lane + 64];
    float v2 = sc[lane + 128];
    float v3 = has3 ? sc[lane + 192] : -1e30f;
    float mx = fmaxf(fmaxf(v0, v1), fmaxf(v2, v3));
#pragma unroll
    for (int off = 32; off; off >>= 1) mx = fmaxf(mx, __shfl_xor(mx, off));
    float e0 = __expf(v0 - mx), e1 = __expf(v1 - mx), e2 = __expf(v2 - mx);
    float e3 = has3 ? __expf(v3 - mx) : 0.f;
    float ts = e0 + e1 + e2 + e3;
#pragma unroll
    for (int off = 32; off; off >>= 1) ts += __shfl_xor(ts, off);
    const float inv = 1.0f / ts;
    if (wave == 0) {                               // one wave publishes exps
      sc2[lane] = e0; sc2[lane + 64] = e1; sc2[lane + 128] = e2;
      if (has3) sc2[lane + 192] = e3;
    }
    __syncthreads();                               // B2: sc2 = exp values

    // ---- fused o-partial + Tw-partial (one phase, dual reduction)
    {
      float oacc = 0.f;
#pragma unroll
      for (int j = 0; j < 50; ++j)
        oacc = fmaf(sc2[p + 4 * j], pf[j], oacc);
      part[tid] = oacc;

      const float4* twr = (const float4*)(Tw + (size_t)d * ED + p * 32);
      float4 tw4[8];
#pragma unroll
      for (int j = 0; j < 8; ++j) tw4[j] = twr[j];
      float tacc = 0.f;
#pragma unroll
      for (int j = 0; j < 8; ++j) {
        tacc = fmaf(u[p * 32 + 4 * j + 0], tw4[j].x, tacc);
        tacc = fmaf(u[p * 32 + 4 * j + 1], tw4[j].y, tacc);
        tacc = fmaf(u[p * 32 + 4 * j + 2], tw4[j].z, tacc);
        tacc = fmaf(u[p * 32 + 4 * j + 3], tw4[j].w, tacc);
      }
      part2[tid] = tacc;

      if (hop < 2) {                               // tile <- next table
#pragma unroll
        for (int j = 0; j < 50; ++j)
          tile[(p + 4 * j) * ED + d] = pf[j];
      }
    }
    __syncthreads();                               // B3: partials ready

    if (tid < ED) {
      float ov = (part[tid] + part[tid + 128] + part[tid + 256]
                  + part[tid + 384]) * inv;
      float dot = part2[tid] + part2[tid + 128] + part2[tid + 256]
                  + part2[tid + 384] + Tb[tid];
      float tk = 1.0f / (1.0f + __expf(-dot));
      u[tid] = (1.0f - tk) * u[tid] + ov * tk;
    }
    __syncthreads();                               // B4: u ready for next hop
  }
  if (tid < ED) U[(size_t)b * ED + tid] = u[tid];
}

// ---------------------------------------------------------------------------
// Kernel C: a_hat = U @ C3^T via f16 MFMA (r6 version: 512 thr, 128 v/block).
// ---------------------------------------------------------------------------
__global__ __launch_bounds__(512) void out_mm_mfma_k(
    const float* __restrict__ U, const _Float16* __restrict__ C3h,
    float* __restrict__ out) {
  __shared__ _Float16 Ub[ED * 136];   // 34,816 B
  const int tid = threadIdx.x;

  {
    const float4* u4 = (const float4*)U;
#pragma unroll
    for (int j = 0; j < 8; ++j) {
      int i = tid + 512 * j;          // float4 index
      float4 f = u4[i];
      int row = i >> 5;
      int col = (i & 31) * 4;
      f16x4 h;
      h[0] = (_Float16)f.x; h[1] = (_Float16)f.y;
      h[2] = (_Float16)f.z; h[3] = (_Float16)f.w;
      *(f16x4*)&Ub[row * 136 + col] = h;
    }
  }
  __syncthreads();

  const int wave = tid >> 6, lane = tid & 63;
  const int n = lane & 15, q = lane >> 4;
  const int v = blockIdx.x * 128 + wave * 16 + n;
  const bool vok = (v < NV);

  f32x4 acc[8];
#pragma unroll
  for (int mt = 0; mt < 8; ++mt) acc[mt] = (f32x4){0.f, 0.f, 0.f, 0.f};

#pragma unroll
  for (int kt = 0; kt < 4; ++kt) {
    f16x8 bfrag = {};
    if (vok) bfrag = *(const f16x8*)(C3h + (size_t)v * ED + kt * 32 + q * 8);
#pragma unroll
    for (int mt = 0; mt < 8; ++mt) {
      f16x8 afrag = *(const f16x8*)&Ub[(mt * 16 + n) * 136 + kt * 32 + q * 8];
      acc[mt] = __builtin_amdgcn_mfma_f32_16x16x32_f16(afrag, bfrag, acc[mt],
                                                       0, 0, 0);
    }
  }

  if (vok) {
#pragma unroll
    for (int mt = 0; mt < 8; ++mt)
#pragma unroll
      for (int i = 0; i < 4; ++i)
        out[(size_t)(mt * 16 + q * 4 + i) * NV + v] = acc[mt][i];
  }
}

// ---------------------------------------------------------------------------
extern "C" void kernel_launch(void* const* d_in, const int* in_sizes, int n_in,
                              void* d_out, int out_size, void* d_ws, size_t ws_size,
                              hipStream_t stream) {
  const int*   story = (const int*)d_in[0];   // [128,200,50]
  const int*   query = (const int*)d_in[1];   // [128,50]
  const float* C     = (const float*)d_in[2]; // [4,50000,128]
  const float* Tw    = (const float*)d_in[3]; // [128,128]
  const float* Tb    = (const float*)d_in[4]; // [128]
  float* out = (float*)d_out;                 // [128,50000]

  float* wsf = (float*)d_ws;
  float*     Mt  = wsf;                                   // 4*BMD floats
  float*     U   = wsf + (size_t)4 * BMD;                 // 16384 floats
  _Float16*  C3h = (_Float16*)(wsf + (size_t)4 * BMD + NB * ED);

  hipLaunchKernelGGL(cvt_c3_k, dim3(NV * ED / 8 / 256), dim3(256), 0, stream,
                     C + (size_t)3 * NV * ED, C3h);
  hipLaunchKernelGGL(story_embed_k, dim3(NB * NM / 16), dim3(256), 0, stream,
                     story, C, C3h, Mt);
  hipLaunchKernelGGL(hops_k, dim3(NB), dim3(512), 0, stream,
                     query, C, Tw, Tb, Mt, U);
  hipLaunchKernelGGL(out_mm_mfma_k, dim3((NV + 127) / 128), dim3(512), 0, stream,
                     U, C3h, out);
}